// Round 1
// baseline (20616.634 us; speedup 1.0000x reference)
//
#include <hip/hip_runtime.h>
#include <cstddef>
#include <cstdint>

// ---------------------------------------------------------------------------
// DeBERTa forward, MI355X. Round 0: correctness-first, all-f32 vector compute.
// B=8 S=512 HID=768 L=12 NH=12 D=64 FF=3072 M=512 (2M=1024)
// ---------------------------------------------------------------------------

constexpr int B   = 8;
constexpr int S   = 512;
constexpr int HID = 768;
constexpr int L   = 12;
constexpr int NH  = 12;
constexpr int D   = 64;
constexpr int FF  = 3072;
constexpr int M2  = 1024;          // 2*M
constexpr int NTOK = B * S;        // 4096

__device__ inline float wave_sum(float v) {
#pragma unroll
  for (int o = 32; o > 0; o >>= 1) v += __shfl_xor(v, o, 64);
  return v;
}
__device__ inline float wave_max(float v) {
#pragma unroll
  for (int o = 32; o > 0; o >>= 1) v = fmaxf(v, __shfl_xor(v, o, 64));
  return v;
}

// ---- embeddings: x = tok_emb[tok] + sinusoidal_pe + seg_emb[seg] -----------
__global__ void embed_kernel(const int* __restrict__ tok,
                             const int* __restrict__ seg,
                             const float* __restrict__ tok_emb,
                             const float* __restrict__ seg_emb,
                             float* __restrict__ x) {
  int row = blockIdx.x;            // b*S + s
  int s = row & (S - 1);
  int t = tok[row];
  int sg = seg[row];
  for (int c = threadIdx.x; c < HID; c += blockDim.x) {
    int i = c >> 1;
    float ang = (float)s * powf(10000.0f, -2.0f * (float)i / (float)HID);
    float pe = (c & 1) ? cosf(ang) : sinf(ang);
    x[(size_t)row * HID + c] = tok_emb[(size_t)t * HID + c] + pe
                             + seg_emb[(size_t)sg * HID + c];
  }
}

// ---- layernorm: one wave per row (HID=768 = 12*64) --------------------------
__global__ __launch_bounds__(256)
void ln_kernel(const float* __restrict__ in, float* __restrict__ out,
               const float* __restrict__ g, const float* __restrict__ b,
               int nrows) {
  int wave = threadIdx.x >> 6, lane = threadIdx.x & 63;
  int row = blockIdx.x * 4 + wave;
  if (row >= nrows) return;
  const float* xr = in + (size_t)row * HID;
  float v[12];
  float s = 0.f;
#pragma unroll
  for (int i = 0; i < 12; i++) { v[i] = xr[lane + i * 64]; s += v[i]; }
  s = wave_sum(s);
  float mu = s * (1.0f / HID);
  float ss = 0.f;
#pragma unroll
  for (int i = 0; i < 12; i++) { float d = v[i] - mu; ss += d * d; }
  ss = wave_sum(ss);
  float inv = rsqrtf(ss * (1.0f / HID) + 1e-5f);
  float* orow = out + (size_t)row * HID;
#pragma unroll
  for (int i = 0; i < 12; i++) {
    int c = lane + i * 64;
    orow[c] = (v[i] - mu) * inv * g[c] + b[c];
  }
}

// ---- generic f32 GEMM: C = [res +] act(A@W + bias) --------------------------
// A: [Mr,K] row-major, W: [K,N] row-major. Mr%64==0, N%64==0, K%32==0.
__global__ __launch_bounds__(256)
void gemm_kernel(const float* __restrict__ A, const float* __restrict__ W,
                 const float* __restrict__ bias, const float* __restrict__ res,
                 float* __restrict__ C, int Mr, int K, int N, int gelu) {
  __shared__ float As[32][65];   // [kk][rr]
  __shared__ float Ws[32][65];   // [kk][nn]
  int n0 = blockIdx.x * 64, r0 = blockIdx.y * 64;
  int t = threadIdx.x;
  int tx = t & 15, ty = t >> 4;
  float acc[4][4] = {};
  for (int k0 = 0; k0 < K; k0 += 32) {
#pragma unroll
    for (int i = 0; i < 8; i++) {
      int idx = t + i * 256;              // 0..2047
      int kk = idx & 31, rr = idx >> 5;   // 64 rows x 32 k
      As[kk][rr] = A[(size_t)(r0 + rr) * K + k0 + kk];
    }
#pragma unroll
    for (int i = 0; i < 8; i++) {
      int idx = t + i * 256;
      int nn = idx & 63, kk = idx >> 6;   // 32 k x 64 n
      Ws[kk][nn] = W[(size_t)(k0 + kk) * N + n0 + nn];
    }
    __syncthreads();
#pragma unroll
    for (int kk = 0; kk < 32; kk++) {
      float a[4], w[4];
#pragma unroll
      for (int i = 0; i < 4; i++) a[i] = As[kk][ty * 4 + i];
#pragma unroll
      for (int j = 0; j < 4; j++) w[j] = Ws[kk][tx * 4 + j];
#pragma unroll
      for (int i = 0; i < 4; i++)
#pragma unroll
        for (int j = 0; j < 4; j++) acc[i][j] += a[i] * w[j];
    }
    __syncthreads();
  }
#pragma unroll
  for (int i = 0; i < 4; i++) {
    int r = r0 + ty * 4 + i;
#pragma unroll
    for (int j = 0; j < 4; j++) {
      int n = n0 + tx * 4 + j;
      float val = acc[i][j];
      if (bias) val += bias[n];
      if (gelu) val = 0.5f * val * (1.0f + erff(val * 0.70710678118654752f));
      if (res)  val += res[(size_t)r * N + n];
      C[(size_t)r * N + n] = val;
    }
  }
}

// ---- attention scores: (c2c + c2p + p2c)*scale, masked ----------------------
// scores[(b-b0), h, q, k] = scale*( Q.K + Q.pk[q-k+512] + K.pq[k-q+512] )
// pk/pq band for a 32x32 tile is 63 contiguous rows -> stage in LDS.
__global__ __launch_bounds__(256)
void scores_kernel(const float* __restrict__ qb, const float* __restrict__ kb,
                   const float* __restrict__ pk, const float* __restrict__ pq,
                   const int* __restrict__ tok, float* __restrict__ scores,
                   int b0) {
  __shared__ float Qs[32][65], Ks[32][65];
  __shared__ float PKs[63][65], PQs[63][65];
  int h = blockIdx.z % NH;
  int b = b0 + blockIdx.z / NH;
  int q0 = blockIdx.y * 32, k0 = blockIdx.x * 32;
  int t = threadIdx.x;
#pragma unroll
  for (int i = 0; i < 8; i++) {
    int idx = t + i * 256;              // 0..2047 = 32 rows x 64 d
    int d = idx & 63, r = idx >> 6;
    Qs[r][d] = qb[(size_t)(b * S + q0 + r) * HID + h * 64 + d];
    Ks[r][d] = kb[(size_t)(b * S + k0 + r) * HID + h * 64 + d];
  }
  int c1 = q0 - k0 + 512;  // pk band center (rows c1-31 .. c1+31, all in [0,1024))
  int c2 = k0 - q0 + 512;
  for (int idx = t; idx < 63 * 64; idx += 256) {
    int d = idx & 63, tt = idx >> 6;
    PKs[tt][d] = pk[(size_t)(c1 - 31 + tt) * HID + h * 64 + d];
    PQs[tt][d] = pq[(size_t)(c2 - 31 + tt) * HID + h * 64 + d];
  }
  __syncthreads();
  int iq = t >> 3, ik0 = (t & 7) * 4;
  float acc[4] = {};
  for (int d = 0; d < D; d++) {
    float qv = Qs[iq][d];
#pragma unroll
    for (int j = 0; j < 4; j++) {
      int ik = ik0 + j;
      float kv = Ks[ik][d];
      acc[j] += qv * kv + qv * PKs[iq - ik + 31][d] + kv * PQs[ik - iq + 31][d];
    }
  }
  const float scale = 0.07216878364870323f;   // 1/sqrt(3*64)
#pragma unroll
  for (int j = 0; j < 4; j++) {
    int ik = ik0 + j;
    float val = acc[j] * scale;
    if (tok[b * S + k0 + ik] == 0) val = -1e9f;  // mask invalid keys
    scores[(((size_t)(b - b0) * NH + h) * S + q0 + iq) * S + k0 + ik] = val;
  }
}

// ---- row softmax over 512 keys, one wave per row ----------------------------
__global__ __launch_bounds__(256)
void softmax_kernel(float* __restrict__ scores, int nrows) {
  int wave = threadIdx.x >> 6, lane = threadIdx.x & 63;
  int row = blockIdx.x * 4 + wave;
  if (row >= nrows) return;
  float* p = scores + (size_t)row * S;
  float v[8];
  float mx = -1e30f;
#pragma unroll
  for (int i = 0; i < 8; i++) { v[i] = p[lane + i * 64]; mx = fmaxf(mx, v[i]); }
  mx = wave_max(mx);
  float s = 0.f;
#pragma unroll
  for (int i = 0; i < 8; i++) { v[i] = __expf(v[i] - mx); s += v[i]; }
  s = wave_sum(s);
  float inv = 1.0f / s;
#pragma unroll
  for (int i = 0; i < 8; i++) p[lane + i * 64] = v[i] * inv;
}

// ---- ctx = attn @ V (per b,h: [512,512]@[512,64]) ---------------------------
__global__ __launch_bounds__(256)
void ctx_kernel(const float* __restrict__ attn, const float* __restrict__ vb,
                float* __restrict__ ctx, int b0) {
  __shared__ float As[32][65];   // [kk][qq]
  __shared__ float Vs[32][65];   // [kk][dd]
  int h = blockIdx.y % NH;
  int b = b0 + blockIdx.y / NH;
  int q0 = blockIdx.x * 64;
  int t = threadIdx.x, tx = t & 15, ty = t >> 4;
  const float* A = attn + ((size_t)(b - b0) * NH + h) * S * S;
  float acc[4][4] = {};
  for (int k0 = 0; k0 < S; k0 += 32) {
#pragma unroll
    for (int i = 0; i < 8; i++) {
      int idx = t + i * 256;              // 64 q x 32 k
      int kk = idx & 31, qq = idx >> 5;
      As[kk][qq] = A[(size_t)(q0 + qq) * S + k0 + kk];
    }
#pragma unroll
    for (int i = 0; i < 8; i++) {
      int idx = t + i * 256;              // 32 k x 64 d
      int dd = idx & 63, kk = idx >> 6;
      Vs[kk][dd] = vb[(size_t)(b * S + k0 + kk) * HID + h * 64 + dd];
    }
    __syncthreads();
#pragma unroll
    for (int kk = 0; kk < 32; kk++) {
      float a[4], w[4];
#pragma unroll
      for (int i = 0; i < 4; i++) a[i] = As[kk][ty * 4 + i];
#pragma unroll
      for (int j = 0; j < 4; j++) w[j] = Vs[kk][tx * 4 + j];
#pragma unroll
      for (int i = 0; i < 4; i++)
#pragma unroll
        for (int j = 0; j < 4; j++) acc[i][j] += a[i] * w[j];
    }
    __syncthreads();
  }
#pragma unroll
  for (int i = 0; i < 4; i++) {
    int qq = q0 + ty * 4 + i;
#pragma unroll
    for (int j = 0; j < 4; j++) {
      int dd = tx * 4 + j;
      ctx[(size_t)(b * S + qq) * HID + h * 64 + dd] = acc[i][j];
    }
  }
}

// ---------------------------------------------------------------------------
extern "C" void kernel_launch(void* const* d_in, const int* in_sizes, int n_in,
                              void* d_out, int out_size, void* d_ws,
                              size_t ws_size, hipStream_t stream) {
  (void)in_sizes; (void)n_in; (void)out_size;
  const int*   tok     = (const int*)d_in[0];
  const int*   seg     = (const int*)d_in[1];
  const float* tok_emb = (const float*)d_in[2];
  const float* seg_emb = (const float*)d_in[3];
  const float* Wq  = (const float*)d_in[4];
  const float* bq  = (const float*)d_in[5];
  const float* Wk  = (const float*)d_in[6];
  const float* bk  = (const float*)d_in[7];
  const float* Wv  = (const float*)d_in[8];
  const float* bv  = (const float*)d_in[9];
  const float* Wo  = (const float*)d_in[10];
  const float* bo  = (const float*)d_in[11];
  const float* Wpk = (const float*)d_in[12];
  const float* Wpq = (const float*)d_in[13];
  const float* rel = (const float*)d_in[14];
  const float* ln1g = (const float*)d_in[15];
  const float* ln1b = (const float*)d_in[16];
  const float* ln2g = (const float*)d_in[17];
  const float* ln2b = (const float*)d_in[18];
  const float* W1  = (const float*)d_in[19];
  const float* b1  = (const float*)d_in[20];
  const float* W2  = (const float*)d_in[21];
  const float* b2  = (const float*)d_in[22];
  const float* lnfg = (const float*)d_in[23];
  const float* lnfb = (const float*)d_in[24];
  float* out = (float*)d_out;

  // workspace layout (all f32)
  float* ws  = (float*)d_ws;
  const size_t XSZ = (size_t)NTOK * HID;       // 3,145,728
  float* x   = ws;
  float* h   = x  + XSZ;
  float* qb  = h  + XSZ;
  float* kb  = qb + XSZ;
  float* vb  = kb + XSZ;
  float* cx  = vb + XSZ;
  float* pkb = cx + XSZ;
  float* pqb = pkb + (size_t)M2 * HID;
  float* big = pqb + (size_t)M2 * HID;
  // big region: scores for nb batches, aliased with FFN intermediate.
  const size_t SC1 = (size_t)NH * S * S;       // per-batch scores: 3,145,728
  const size_t FFSZ = (size_t)NTOK * FF;       // 12,582,912
  size_t need8 = (size_t)(big - ws) + ((SC1 * 8 > FFSZ) ? SC1 * 8 : FFSZ);
  int nb = (ws_size >= need8 * sizeof(float)) ? 8 : 1;  // deterministic (ws_size fixed)
  float* scores = big;
  float* ff     = big;   // alias: scores dead before FFN, ff dead before next attn

  embed_kernel<<<NTOK, 256, 0, stream>>>(tok, seg, tok_emb, seg_emb, x);

  for (int l = 0; l < L; l++) {
    const float* lWq = Wq + (size_t)l * HID * HID;
    const float* lWk = Wk + (size_t)l * HID * HID;
    const float* lWv = Wv + (size_t)l * HID * HID;
    const float* lWo = Wo + (size_t)l * HID * HID;
    const float* lWpk = Wpk + (size_t)l * HID * HID;
    const float* lWpq = Wpq + (size_t)l * HID * HID;
    const float* lW1 = W1 + (size_t)l * HID * FF;
    const float* lW2 = W2 + (size_t)l * FF * HID;
    const float* lrel = rel + (size_t)l * M2 * HID;

    // ---- attention sublayer (pre-norm) ----
    ln_kernel<<<NTOK / 4, 256, 0, stream>>>(x, h, ln1g + l * HID, ln1b + l * HID, NTOK);
    gemm_kernel<<<dim3(HID / 64, NTOK / 64), 256, 0, stream>>>(
        h, lWq, bq + l * HID, nullptr, qb, NTOK, HID, HID, 0);
    gemm_kernel<<<dim3(HID / 64, NTOK / 64), 256, 0, stream>>>(
        h, lWk, bk + l * HID, nullptr, kb, NTOK, HID, HID, 0);
    gemm_kernel<<<dim3(HID / 64, NTOK / 64), 256, 0, stream>>>(
        h, lWv, bv + l * HID, nullptr, vb, NTOK, HID, HID, 0);
    gemm_kernel<<<dim3(HID / 64, M2 / 64), 256, 0, stream>>>(
        lrel, lWpk, nullptr, nullptr, pkb, M2, HID, HID, 0);
    gemm_kernel<<<dim3(HID / 64, M2 / 64), 256, 0, stream>>>(
        lrel, lWpq, nullptr, nullptr, pqb, M2, HID, HID, 0);

    for (int b0 = 0; b0 < B; b0 += nb) {
      scores_kernel<<<dim3(S / 32, S / 32, nb * NH), 256, 0, stream>>>(
          qb, kb, pkb, pqb, tok, scores, b0);
      softmax_kernel<<<(nb * NH * S) / 4, 256, 0, stream>>>(scores, nb * NH * S);
      ctx_kernel<<<dim3(S / 64, nb * NH), 256, 0, stream>>>(scores, vb, cx, b0);
    }
    gemm_kernel<<<dim3(HID / 64, NTOK / 64), 256, 0, stream>>>(
        cx, lWo, bo + l * HID, x, x, NTOK, HID, HID, 0);

    // ---- feedforward sublayer (pre-norm) ----
    ln_kernel<<<NTOK / 4, 256, 0, stream>>>(x, h, ln2g + l * HID, ln2b + l * HID, NTOK);
    gemm_kernel<<<dim3(FF / 64, NTOK / 64), 256, 0, stream>>>(
        h, lW1, b1 + l * FF, nullptr, ff, NTOK, HID, FF, 1);
    gemm_kernel<<<dim3(HID / 64, NTOK / 64), 256, 0, stream>>>(
        ff, lW2, b2 + l * HID, x, x, NTOK, FF, HID, 0);
  }

  ln_kernel<<<NTOK / 4, 256, 0, stream>>>(x, out, lnfg, lnfb, NTOK);
}

// Round 2
// 9014.223 us; speedup vs baseline: 2.2871x; 2.2871x over previous
//
#include <hip/hip_runtime.h>
#include <hip/hip_bf16.h>
#include <cstddef>
#include <cstdint>

// ---------------------------------------------------------------------------
// DeBERTa forward, MI355X. Round 1: bf16 MFMA GEMMs (m97 structure),
// f32 attention unchanged. B=8 S=512 HID=768 L=12 NH=12 D=64 FF=3072 2M=1024
// ---------------------------------------------------------------------------

constexpr int B   = 8;
constexpr int S   = 512;
constexpr int HID = 768;
constexpr int L   = 12;
constexpr int NH  = 12;
constexpr int D   = 64;
constexpr int FF  = 3072;
constexpr int M2  = 1024;          // 2*M
constexpr int NTOK = B * S;        // 4096

using f32x4 = __attribute__((ext_vector_type(4))) float;
using s16x8 = __attribute__((ext_vector_type(8))) short;

__device__ inline float wave_sum(float v) {
#pragma unroll
  for (int o = 32; o > 0; o >>= 1) v += __shfl_xor(v, o, 64);
  return v;
}
__device__ inline float wave_max(float v) {
#pragma unroll
  for (int o = 32; o > 0; o >>= 1) v = fmaxf(v, __shfl_xor(v, o, 64));
  return v;
}
__device__ inline unsigned short f2bf(float f) {
  __hip_bfloat16 h = __float2bfloat16(f);
  return *reinterpret_cast<unsigned short*>(&h);
}

// ---- embeddings -------------------------------------------------------------
__global__ void embed_kernel(const int* __restrict__ tok,
                             const int* __restrict__ seg,
                             const float* __restrict__ tok_emb,
                             const float* __restrict__ seg_emb,
                             float* __restrict__ x) {
  int row = blockIdx.x;            // b*S + s
  int s = row & (S - 1);
  int t = tok[row];
  int sg = seg[row];
  for (int c = threadIdx.x; c < HID; c += blockDim.x) {
    int i = c >> 1;
    float ang = (float)s * powf(10000.0f, -2.0f * (float)i / (float)HID);
    float pe = (c & 1) ? cosf(ang) : sinf(ang);
    x[(size_t)row * HID + c] = tok_emb[(size_t)t * HID + c] + pe
                             + seg_emb[(size_t)sg * HID + c];
  }
}

// ---- layernorm: one wave per row; optional bf16 output ----------------------
template <int BF16OUT>
__global__ __launch_bounds__(256)
void ln_kernel(const float* __restrict__ in, void* __restrict__ outp,
               const float* __restrict__ g, const float* __restrict__ b,
               int nrows) {
  int wave = threadIdx.x >> 6, lane = threadIdx.x & 63;
  int row = blockIdx.x * 4 + wave;
  if (row >= nrows) return;
  const float* xr = in + (size_t)row * HID;
  float v[12];
  float s = 0.f;
#pragma unroll
  for (int i = 0; i < 12; i++) { v[i] = xr[lane + i * 64]; s += v[i]; }
  s = wave_sum(s);
  float mu = s * (1.0f / HID);
  float ss = 0.f;
#pragma unroll
  for (int i = 0; i < 12; i++) { float d = v[i] - mu; ss += d * d; }
  ss = wave_sum(ss);
  float inv = rsqrtf(ss * (1.0f / HID) + 1e-5f);
#pragma unroll
  for (int i = 0; i < 12; i++) {
    int c = lane + i * 64;
    float o = (v[i] - mu) * inv * g[c] + b[c];
    if (BF16OUT)
      ((unsigned short*)outp)[(size_t)row * HID + c] = f2bf(o);
    else
      ((float*)outp)[(size_t)row * HID + c] = o;
  }
}

// ---- transpose+convert: src [K,N] f32 -> dst [N,K] bf16 ---------------------
__global__ __launch_bounds__(256)
void transpose_kernel(const float* __restrict__ src,
                      unsigned short* __restrict__ dst, int K, int N) {
  __shared__ float tile[32][33];
  int nt = blockIdx.x * 32, kt = blockIdx.y * 32;
  int tx = threadIdx.x & 31, ty = threadIdx.x >> 5;
#pragma unroll
  for (int i = 0; i < 4; i++)
    tile[ty + i * 8][tx] = src[(size_t)(kt + ty + i * 8) * N + nt + tx];
  __syncthreads();
#pragma unroll
  for (int i = 0; i < 4; i++)
    dst[(size_t)(nt + ty + i * 8) * K + kt + tx] = f2bf(tile[tx][ty + i * 8]);
}

// batched: 6 square [HID,HID] weights in one dispatch (z picks weight)
__global__ __launch_bounds__(256)
void transpose6_kernel(const float* s0, const float* s1, const float* s2,
                       const float* s3, const float* s4, const float* s5,
                       unsigned short* __restrict__ dst) {
  const float* srcs[6] = {s0, s1, s2, s3, s4, s5};
  const float* src = srcs[blockIdx.z];
  unsigned short* d = dst + (size_t)blockIdx.z * HID * HID;
  __shared__ float tile[32][33];
  int nt = blockIdx.x * 32, kt = blockIdx.y * 32;
  int tx = threadIdx.x & 31, ty = threadIdx.x >> 5;
#pragma unroll
  for (int i = 0; i < 4; i++)
    tile[ty + i * 8][tx] = src[(size_t)(kt + ty + i * 8) * HID + nt + tx];
  __syncthreads();
#pragma unroll
  for (int i = 0; i < 4; i++)
    d[(size_t)(nt + ty + i * 8) * HID + kt + tx] = f2bf(tile[tx][ty + i * 8]);
}

// ---- elementwise f32 -> bf16 ------------------------------------------------
__global__ void conv_bf16_kernel(const float* __restrict__ src,
                                 unsigned short* __restrict__ dst, int n) {
  int i = blockIdx.x * 256 + threadIdx.x;
  if (i < n) dst[i] = f2bf(src[i]);
}

// ---- bf16 MFMA GEMM (m97 structure): C = [res +] act(A@B + bias) ------------
// A: [Mr,K] bf16 row-major.  Bt: [N,K] bf16 row-major (pre-transposed weight).
// Mr%128==0, N%128==0, K%32==0.  256 threads = 4 waves, 128x128 tile, BK=32.
template <int OUT_BF16, int GELU>
__global__ __launch_bounds__(256)
void mfma_gemm(const unsigned short* __restrict__ A,
               const unsigned short* __restrict__ Bt,
               const float* __restrict__ bias, const float* __restrict__ res,
               void* __restrict__ C, int Mr, int K, int N) {
  __shared__ unsigned short As[128 * 32];   // [row][k] 64B rows
  __shared__ unsigned short Bs[128 * 32];   // [n][k]   64B rows
  int t = threadIdx.x;
  int wave = t >> 6, lane = t & 63;
  int r0 = blockIdx.y * 128, n0 = blockIdx.x * 128;
  int wr = (wave >> 1) * 64, wc = (wave & 1) * 64;

  f32x4 acc[4][4] = {};

  // per-wave staging coords: wave covers 32 rows of each tile, 2 issues x 16 rows
  int srow = (lane >> 2);           // 0..15
  int selem = (lane & 3) * 8;       // k-element offset of this lane's 16B

  for (int k0 = 0; k0 < K; k0 += 32) {
    __syncthreads();   // previous iteration's LDS reads complete
    {
      const unsigned short* gA =
          A + (size_t)(r0 + wave * 32 + srow) * K + k0 + selem;
      const unsigned short* gB =
          Bt + (size_t)(n0 + wave * 32 + srow) * K + k0 + selem;
      unsigned short* lA = &As[(wave * 32) * 32];
      unsigned short* lB = &Bs[(wave * 32) * 32];
      __builtin_amdgcn_global_load_lds(
          (const __attribute__((address_space(1))) void*)gA,
          (__attribute__((address_space(3))) void*)lA, 16, 0, 0);
      __builtin_amdgcn_global_load_lds(
          (const __attribute__((address_space(1))) void*)(gA + (size_t)16 * K),
          (__attribute__((address_space(3))) void*)(lA + 16 * 32), 16, 0, 0);
      __builtin_amdgcn_global_load_lds(
          (const __attribute__((address_space(1))) void*)gB,
          (__attribute__((address_space(3))) void*)lB, 16, 0, 0);
      __builtin_amdgcn_global_load_lds(
          (const __attribute__((address_space(1))) void*)(gB + (size_t)16 * K),
          (__attribute__((address_space(3))) void*)(lB + 16 * 32), 16, 0, 0);
    }
    __syncthreads();   // drains vmcnt; tiles visible

    s16x8 af[4], bf[4];
#pragma unroll
    for (int m = 0; m < 4; m++)
      af[m] = *(const s16x8*)&As[(wr + m * 16 + (lane & 15)) * 32 + (lane >> 4) * 8];
#pragma unroll
    for (int n = 0; n < 4; n++)
      bf[n] = *(const s16x8*)&Bs[(wc + n * 16 + (lane & 15)) * 32 + (lane >> 4) * 8];
#pragma unroll
    for (int m = 0; m < 4; m++)
#pragma unroll
      for (int n = 0; n < 4; n++)
        acc[m][n] = __builtin_amdgcn_mfma_f32_16x16x32_bf16(af[m], bf[n],
                                                            acc[m][n], 0, 0, 0);
  }

  // epilogue: C/D layout col=lane&15, row=(lane>>4)*4+j  [m89-verified]
#pragma unroll
  for (int n = 0; n < 4; n++) {
    int c = n0 + wc + n * 16 + (lane & 15);
    float bv = bias ? bias[c] : 0.f;
#pragma unroll
    for (int m = 0; m < 4; m++) {
      int rb = r0 + wr + m * 16 + ((lane >> 4) << 2);
#pragma unroll
      for (int j = 0; j < 4; j++) {
        int r = rb + j;
        float val = acc[m][n][j] + bv;
        if (GELU) val = 0.5f * val * (1.0f + erff(val * 0.70710678118654752f));
        if (res)  val += res[(size_t)r * N + c];
        if (OUT_BF16)
          ((unsigned short*)C)[(size_t)r * N + c] = f2bf(val);
        else
          ((float*)C)[(size_t)r * N + c] = val;
      }
    }
  }
}

// ---- attention scores: (c2c + c2p + p2c)*scale, masked (f32) ----------------
__global__ __launch_bounds__(256)
void scores_kernel(const float* __restrict__ qb, const float* __restrict__ kb,
                   const float* __restrict__ pk, const float* __restrict__ pq,
                   const int* __restrict__ tok, float* __restrict__ scores,
                   int b0) {
  __shared__ float Qs[32][65], Ks[32][65];
  __shared__ float PKs[63][65], PQs[63][65];
  int h = blockIdx.z % NH;
  int b = b0 + blockIdx.z / NH;
  int q0 = blockIdx.y * 32, k0 = blockIdx.x * 32;
  int t = threadIdx.x;
#pragma unroll
  for (int i = 0; i < 8; i++) {
    int idx = t + i * 256;
    int d = idx & 63, r = idx >> 6;
    Qs[r][d] = qb[(size_t)(b * S + q0 + r) * HID + h * 64 + d];
    Ks[r][d] = kb[(size_t)(b * S + k0 + r) * HID + h * 64 + d];
  }
  int c1 = q0 - k0 + 512;
  int c2 = k0 - q0 + 512;
  for (int idx = t; idx < 63 * 64; idx += 256) {
    int d = idx & 63, tt = idx >> 6;
    PKs[tt][d] = pk[(size_t)(c1 - 31 + tt) * HID + h * 64 + d];
    PQs[tt][d] = pq[(size_t)(c2 - 31 + tt) * HID + h * 64 + d];
  }
  __syncthreads();
  int iq = t >> 3, ik0 = (t & 7) * 4;
  float acc[4] = {};
  for (int d = 0; d < D; d++) {
    float qv = Qs[iq][d];
#pragma unroll
    for (int j = 0; j < 4; j++) {
      int ik = ik0 + j;
      float kv = Ks[ik][d];
      acc[j] += qv * kv + qv * PKs[iq - ik + 31][d] + kv * PQs[ik - iq + 31][d];
    }
  }
  const float scale = 0.07216878364870323f;   // 1/sqrt(3*64)
#pragma unroll
  for (int j = 0; j < 4; j++) {
    int ik = ik0 + j;
    float val = acc[j] * scale;
    if (tok[b * S + k0 + ik] == 0) val = -1e9f;
    scores[(((size_t)(b - b0) * NH + h) * S + q0 + iq) * S + k0 + ik] = val;
  }
}

// ---- row softmax over 512 keys ----------------------------------------------
__global__ __launch_bounds__(256)
void softmax_kernel(float* __restrict__ scores, int nrows) {
  int wave = threadIdx.x >> 6, lane = threadIdx.x & 63;
  int row = blockIdx.x * 4 + wave;
  if (row >= nrows) return;
  float* p = scores + (size_t)row * S;
  float v[8];
  float mx = -1e30f;
#pragma unroll
  for (int i = 0; i < 8; i++) { v[i] = p[lane + i * 64]; mx = fmaxf(mx, v[i]); }
  mx = wave_max(mx);
  float s = 0.f;
#pragma unroll
  for (int i = 0; i < 8; i++) { v[i] = __expf(v[i] - mx); s += v[i]; }
  s = wave_sum(s);
  float inv = 1.0f / s;
#pragma unroll
  for (int i = 0; i < 8; i++) p[lane + i * 64] = v[i] * inv;
}

// ---- ctx = attn @ V -> bf16 out ----------------------------------------------
__global__ __launch_bounds__(256)
void ctx_kernel(const float* __restrict__ attn, const float* __restrict__ vb,
                unsigned short* __restrict__ ctx, int b0) {
  __shared__ float As_[32][65];
  __shared__ float Vs[32][65];
  int h = blockIdx.y % NH;
  int b = b0 + blockIdx.y / NH;
  int q0 = blockIdx.x * 64;
  int t = threadIdx.x, tx = t & 15, ty = t >> 4;
  const float* A = attn + ((size_t)(b - b0) * NH + h) * S * S;
  float acc[4][4] = {};
  for (int k0 = 0; k0 < S; k0 += 32) {
#pragma unroll
    for (int i = 0; i < 8; i++) {
      int idx = t + i * 256;
      int kk = idx & 31, qq = idx >> 5;
      As_[kk][qq] = A[(size_t)(q0 + qq) * S + k0 + kk];
    }
#pragma unroll
    for (int i = 0; i < 8; i++) {
      int idx = t + i * 256;
      int dd = idx & 63, kk = idx >> 6;
      Vs[kk][dd] = vb[(size_t)(b * S + k0 + kk) * HID + h * 64 + dd];
    }
    __syncthreads();
#pragma unroll
    for (int kk = 0; kk < 32; kk++) {
      float a[4], w[4];
#pragma unroll
      for (int i = 0; i < 4; i++) a[i] = As_[kk][ty * 4 + i];
#pragma unroll
      for (int j = 0; j < 4; j++) w[j] = Vs[kk][tx * 4 + j];
#pragma unroll
      for (int i = 0; i < 4; i++)
#pragma unroll
        for (int j = 0; j < 4; j++) acc[i][j] += a[i] * w[j];
    }
    __syncthreads();
  }
#pragma unroll
  for (int i = 0; i < 4; i++) {
    int qq = q0 + ty * 4 + i;
#pragma unroll
    for (int j = 0; j < 4; j++) {
      int dd = tx * 4 + j;
      ctx[(size_t)(b * S + qq) * HID + h * 64 + dd] = f2bf(acc[i][j]);
    }
  }
}

// ---------------------------------------------------------------------------
extern "C" void kernel_launch(void* const* d_in, const int* in_sizes, int n_in,
                              void* d_out, int out_size, void* d_ws,
                              size_t ws_size, hipStream_t stream) {
  (void)in_sizes; (void)n_in; (void)out_size;
  const int*   tok     = (const int*)d_in[0];
  const int*   seg     = (const int*)d_in[1];
  const float* tok_emb = (const float*)d_in[2];
  const float* seg_emb = (const float*)d_in[3];
  const float* Wq  = (const float*)d_in[4];
  const float* bq  = (const float*)d_in[5];
  const float* Wk  = (const float*)d_in[6];
  const float* bk  = (const float*)d_in[7];
  const float* Wv  = (const float*)d_in[8];
  const float* bv  = (const float*)d_in[9];
  const float* Wo  = (const float*)d_in[10];
  const float* bo  = (const float*)d_in[11];
  const float* Wpk = (const float*)d_in[12];
  const float* Wpq = (const float*)d_in[13];
  const float* rel = (const float*)d_in[14];
  const float* ln1g = (const float*)d_in[15];
  const float* ln1b = (const float*)d_in[16];
  const float* ln2g = (const float*)d_in[17];
  const float* ln2b = (const float*)d_in[18];
  const float* W1  = (const float*)d_in[19];
  const float* b1  = (const float*)d_in[20];
  const float* W2  = (const float*)d_in[21];
  const float* b2  = (const float*)d_in[22];
  const float* lnfg = (const float*)d_in[23];
  const float* lnfb = (const float*)d_in[24];
  float* out = (float*)d_out;

  // ---- workspace layout ----
  char* base = (char*)d_ws;
  size_t off = 0;
  auto alloc = [&](size_t bytes) -> void* {
    void* p = base + off;
    off += (bytes + 255) & ~(size_t)255;
    return p;
  };
  const size_t XSZ = (size_t)NTOK * HID;
  float* x   = (float*)alloc(XSZ * 4);
  float* qb  = (float*)alloc(XSZ * 4);
  float* kb  = (float*)alloc(XSZ * 4);
  float* vb  = (float*)alloc(XSZ * 4);
  float* pkb = (float*)alloc((size_t)M2 * HID * 4);
  float* pqb = (float*)alloc((size_t)M2 * HID * 4);
  unsigned short* act16 = (unsigned short*)alloc(XSZ * 2);          // ln out / ctx out
  unsigned short* ff16  = (unsigned short*)alloc((size_t)NTOK * FF * 2);
  unsigned short* rel16 = (unsigned short*)alloc((size_t)M2 * HID * 2);
  unsigned short* wt6   = (unsigned short*)alloc((size_t)6 * HID * HID * 2);
  unsigned short* wt1   = (unsigned short*)alloc((size_t)HID * FF * 2);
  unsigned short* wt2   = (unsigned short*)alloc((size_t)HID * FF * 2);
  // scores region: nb batches of [NH,S,S] f32
  size_t fixed = off;
  size_t sc8 = (size_t)8 * NH * S * S * 4;
  int nb = (ws_size >= fixed + sc8) ? 8 : 1;   // deterministic (ws_size fixed)
  float* scores = (float*)alloc((size_t)nb * NH * S * S * 4);

  const size_t WSQ = (size_t)HID * HID;

  embed_kernel<<<NTOK, 256, 0, stream>>>(tok, seg, tok_emb, seg_emb, x);

  for (int l = 0; l < L; l++) {
    const float* lWq = Wq + (size_t)l * WSQ;
    const float* lWk = Wk + (size_t)l * WSQ;
    const float* lWv = Wv + (size_t)l * WSQ;
    const float* lWo = Wo + (size_t)l * WSQ;
    const float* lWpk = Wpk + (size_t)l * WSQ;
    const float* lWpq = Wpq + (size_t)l * WSQ;
    const float* lW1 = W1 + (size_t)l * HID * FF;
    const float* lW2 = W2 + (size_t)l * FF * HID;
    const float* lrel = rel + (size_t)l * M2 * HID;

    // weight prep: transpose+bf16 (slots: 0=q 1=k 2=v 3=o 4=pk 5=pq)
    transpose6_kernel<<<dim3(HID / 32, HID / 32, 6), 256, 0, stream>>>(
        lWq, lWk, lWv, lWo, lWpk, lWpq, wt6);
    transpose_kernel<<<dim3(FF / 32, HID / 32), 256, 0, stream>>>(lW1, wt1, HID, FF);
    transpose_kernel<<<dim3(HID / 32, FF / 32), 256, 0, stream>>>(lW2, wt2, FF, HID);
    conv_bf16_kernel<<<(M2 * HID + 255) / 256, 256, 0, stream>>>(lrel, rel16, M2 * HID);

    // ---- attention sublayer (pre-norm) ----
    ln_kernel<1><<<NTOK / 4, 256, 0, stream>>>(x, act16, ln1g + l * HID,
                                               ln1b + l * HID, NTOK);
    mfma_gemm<0, 0><<<dim3(HID / 128, NTOK / 128), 256, 0, stream>>>(
        act16, wt6 + 0 * WSQ, bq + l * HID, nullptr, qb, NTOK, HID, HID);
    mfma_gemm<0, 0><<<dim3(HID / 128, NTOK / 128), 256, 0, stream>>>(
        act16, wt6 + 1 * WSQ, bk + l * HID, nullptr, kb, NTOK, HID, HID);
    mfma_gemm<0, 0><<<dim3(HID / 128, NTOK / 128), 256, 0, stream>>>(
        act16, wt6 + 2 * WSQ, bv + l * HID, nullptr, vb, NTOK, HID, HID);
    mfma_gemm<0, 0><<<dim3(HID / 128, M2 / 128), 256, 0, stream>>>(
        rel16, wt6 + 4 * WSQ, nullptr, nullptr, pkb, M2, HID, HID);
    mfma_gemm<0, 0><<<dim3(HID / 128, M2 / 128), 256, 0, stream>>>(
        rel16, wt6 + 5 * WSQ, nullptr, nullptr, pqb, M2, HID, HID);

    for (int b0 = 0; b0 < B; b0 += nb) {
      scores_kernel<<<dim3(S / 32, S / 32, nb * NH), 256, 0, stream>>>(
          qb, kb, pkb, pqb, tok, scores, b0);
      softmax_kernel<<<(nb * NH * S) / 4, 256, 0, stream>>>(scores, nb * NH * S);
      ctx_kernel<<<dim3(S / 64, nb * NH), 256, 0, stream>>>(scores, vb, act16, b0);
    }
    mfma_gemm<0, 0><<<dim3(HID / 128, NTOK / 128), 256, 0, stream>>>(
        act16, wt6 + 3 * WSQ, bo + l * HID, x, x, NTOK, HID, HID);

    // ---- feedforward sublayer (pre-norm) ----
    ln_kernel<1><<<NTOK / 4, 256, 0, stream>>>(x, act16, ln2g + l * HID,
                                               ln2b + l * HID, NTOK);
    mfma_gemm<1, 1><<<dim3(FF / 128, NTOK / 128), 256, 0, stream>>>(
        act16, wt1, b1 + l * FF, nullptr, ff16, NTOK, HID, FF);
    mfma_gemm<0, 0><<<dim3(HID / 128, NTOK / 128), 256, 0, stream>>>(
        ff16, wt2, b2 + l * HID, x, x, NTOK, FF, HID);
  }

  ln_kernel<0><<<NTOK / 4, 256, 0, stream>>>(x, out, lnfg, lnfb, NTOK);
}

// Round 3
// 5022.894 us; speedup vs baseline: 4.1045x; 1.7946x over previous
//
#include <hip/hip_runtime.h>
#include <hip/hip_bf16.h>
#include <cstddef>
#include <cstdint>

// ---------------------------------------------------------------------------
// DeBERTa forward, MI355X. Round 3: full-MFMA attention (band-GEMM scores,
// bf16 probs, MFMA PV) + bf16 MFMA GEMMs.
// B=8 S=512 HID=768 L=12 NH=12 D=64 FF=3072 2M=1024
// ---------------------------------------------------------------------------

constexpr int B   = 8;
constexpr int S   = 512;
constexpr int HID = 768;
constexpr int L   = 12;
constexpr int NH  = 12;
constexpr int D   = 64;
constexpr int FF  = 3072;
constexpr int M2  = 1024;          // 2*M
constexpr int NTOK = B * S;        // 4096

using f32x4 = __attribute__((ext_vector_type(4))) float;
using s16x8 = __attribute__((ext_vector_type(8))) short;

__device__ inline float wave_sum(float v) {
#pragma unroll
  for (int o = 32; o > 0; o >>= 1) v += __shfl_xor(v, o, 64);
  return v;
}
__device__ inline float wave_max(float v) {
#pragma unroll
  for (int o = 32; o > 0; o >>= 1) v = fmaxf(v, __shfl_xor(v, o, 64));
  return v;
}
__device__ inline unsigned short f2bf(float f) {
  __hip_bfloat16 h = __float2bfloat16(f);
  return *reinterpret_cast<unsigned short*>(&h);
}
__device__ inline float bf2f(unsigned short u) {
  union { unsigned int i; float f; } x;
  x.i = ((unsigned int)u) << 16;
  return x.f;
}

// ---- embeddings -------------------------------------------------------------
__global__ void embed_kernel(const int* __restrict__ tok,
                             const int* __restrict__ seg,
                             const float* __restrict__ tok_emb,
                             const float* __restrict__ seg_emb,
                             float* __restrict__ x) {
  int row = blockIdx.x;            // b*S + s
  int s = row & (S - 1);
  int t = tok[row];
  int sg = seg[row];
  for (int c = threadIdx.x; c < HID; c += blockDim.x) {
    int i = c >> 1;
    float ang = (float)s * powf(10000.0f, -2.0f * (float)i / (float)HID);
    float pe = (c & 1) ? cosf(ang) : sinf(ang);
    x[(size_t)row * HID + c] = tok_emb[(size_t)t * HID + c] + pe
                             + seg_emb[(size_t)sg * HID + c];
  }
}

// ---- layernorm: one wave per row; optional bf16 output ----------------------
template <int BF16OUT>
__global__ __launch_bounds__(256)
void ln_kernel(const float* __restrict__ in, void* __restrict__ outp,
               const float* __restrict__ g, const float* __restrict__ b,
               int nrows) {
  int wave = threadIdx.x >> 6, lane = threadIdx.x & 63;
  int row = blockIdx.x * 4 + wave;
  if (row >= nrows) return;
  const float* xr = in + (size_t)row * HID;
  float v[12];
  float s = 0.f;
#pragma unroll
  for (int i = 0; i < 12; i++) { v[i] = xr[lane + i * 64]; s += v[i]; }
  s = wave_sum(s);
  float mu = s * (1.0f / HID);
  float ss = 0.f;
#pragma unroll
  for (int i = 0; i < 12; i++) { float d = v[i] - mu; ss += d * d; }
  ss = wave_sum(ss);
  float inv = rsqrtf(ss * (1.0f / HID) + 1e-5f);
#pragma unroll
  for (int i = 0; i < 12; i++) {
    int c = lane + i * 64;
    float o = (v[i] - mu) * inv * g[c] + b[c];
    if (BF16OUT)
      ((unsigned short*)outp)[(size_t)row * HID + c] = f2bf(o);
    else
      ((float*)outp)[(size_t)row * HID + c] = o;
  }
}

// ---- transpose+convert: src [K,N] f32 -> dst [N,K] bf16 ---------------------
__global__ __launch_bounds__(256)
void transpose_kernel(const float* __restrict__ src,
                      unsigned short* __restrict__ dst, int K, int N) {
  __shared__ float tile[32][33];
  int nt = blockIdx.x * 32, kt = blockIdx.y * 32;
  int tx = threadIdx.x & 31, ty = threadIdx.x >> 5;
#pragma unroll
  for (int i = 0; i < 4; i++)
    tile[ty + i * 8][tx] = src[(size_t)(kt + ty + i * 8) * N + nt + tx];
  __syncthreads();
#pragma unroll
  for (int i = 0; i < 4; i++)
    dst[(size_t)(nt + ty + i * 8) * K + kt + tx] = f2bf(tile[tx][ty + i * 8]);
}

// batched: 6 square [HID,HID] weights in one dispatch (z picks weight)
__global__ __launch_bounds__(256)
void transpose6_kernel(const float* s0, const float* s1, const float* s2,
                       const float* s3, const float* s4, const float* s5,
                       unsigned short* __restrict__ dst) {
  const float* srcs[6] = {s0, s1, s2, s3, s4, s5};
  const float* src = srcs[blockIdx.z];
  unsigned short* d = dst + (size_t)blockIdx.z * HID * HID;
  __shared__ float tile[32][33];
  int nt = blockIdx.x * 32, kt = blockIdx.y * 32;
  int tx = threadIdx.x & 31, ty = threadIdx.x >> 5;
#pragma unroll
  for (int i = 0; i < 4; i++)
    tile[ty + i * 8][tx] = src[(size_t)(kt + ty + i * 8) * HID + nt + tx];
  __syncthreads();
#pragma unroll
  for (int i = 0; i < 4; i++)
    d[(size_t)(nt + ty + i * 8) * HID + kt + tx] = f2bf(tile[tx][ty + i * 8]);
}

// ---- elementwise f32 -> bf16 ------------------------------------------------
__global__ void conv_bf16_kernel(const float* __restrict__ src,
                                 unsigned short* __restrict__ dst, int n) {
  int i = blockIdx.x * 256 + threadIdx.x;
  if (i < n) dst[i] = f2bf(src[i]);
}

// ---- bf16 MFMA GEMM (m97 structure): C = [res +] act(A@B + bias) ------------
// A: [Mr,K] bf16 row-major.  Bt: [N,K] bf16 row-major (pre-transposed weight).
template <int OUT_BF16, int GELU>
__global__ __launch_bounds__(256)
void mfma_gemm(const unsigned short* __restrict__ A,
               const unsigned short* __restrict__ Bt,
               const float* __restrict__ bias, const float* __restrict__ res,
               void* __restrict__ C, int Mr, int K, int N) {
  __shared__ unsigned short As[128 * 32];   // [row][k] 64B rows
  __shared__ unsigned short Bs[128 * 32];   // [n][k]   64B rows
  int t = threadIdx.x;
  int wave = t >> 6, lane = t & 63;
  int r0 = blockIdx.y * 128, n0 = blockIdx.x * 128;
  int wr = (wave >> 1) * 64, wc = (wave & 1) * 64;

  f32x4 acc[4][4] = {};

  int srow = (lane >> 2);           // 0..15
  int selem = (lane & 3) * 8;       // k-element offset of this lane's 16B

  for (int k0 = 0; k0 < K; k0 += 32) {
    __syncthreads();
    {
      const unsigned short* gA =
          A + (size_t)(r0 + wave * 32 + srow) * K + k0 + selem;
      const unsigned short* gB =
          Bt + (size_t)(n0 + wave * 32 + srow) * K + k0 + selem;
      unsigned short* lA = &As[(wave * 32) * 32];
      unsigned short* lB = &Bs[(wave * 32) * 32];
      __builtin_amdgcn_global_load_lds(
          (const __attribute__((address_space(1))) void*)gA,
          (__attribute__((address_space(3))) void*)lA, 16, 0, 0);
      __builtin_amdgcn_global_load_lds(
          (const __attribute__((address_space(1))) void*)(gA + (size_t)16 * K),
          (__attribute__((address_space(3))) void*)(lA + 16 * 32), 16, 0, 0);
      __builtin_amdgcn_global_load_lds(
          (const __attribute__((address_space(1))) void*)gB,
          (__attribute__((address_space(3))) void*)lB, 16, 0, 0);
      __builtin_amdgcn_global_load_lds(
          (const __attribute__((address_space(1))) void*)(gB + (size_t)16 * K),
          (__attribute__((address_space(3))) void*)(lB + 16 * 32), 16, 0, 0);
    }
    __syncthreads();

    s16x8 af[4], bf[4];
#pragma unroll
    for (int m = 0; m < 4; m++)
      af[m] = *(const s16x8*)&As[(wr + m * 16 + (lane & 15)) * 32 + (lane >> 4) * 8];
#pragma unroll
    for (int n = 0; n < 4; n++)
      bf[n] = *(const s16x8*)&Bs[(wc + n * 16 + (lane & 15)) * 32 + (lane >> 4) * 8];
#pragma unroll
    for (int m = 0; m < 4; m++)
#pragma unroll
      for (int n = 0; n < 4; n++)
        acc[m][n] = __builtin_amdgcn_mfma_f32_16x16x32_bf16(af[m], bf[n],
                                                            acc[m][n], 0, 0, 0);
  }

#pragma unroll
  for (int n = 0; n < 4; n++) {
    int c = n0 + wc + n * 16 + (lane & 15);
    float bv = bias ? bias[c] : 0.f;
#pragma unroll
    for (int m = 0; m < 4; m++) {
      int rb = r0 + wr + m * 16 + ((lane >> 4) << 2);
#pragma unroll
      for (int j = 0; j < 4; j++) {
        int r = rb + j;
        float val = acc[m][n][j] + bv;
        if (GELU) val = 0.5f * val * (1.0f + erff(val * 0.70710678118654752f));
        if (res)  val += res[(size_t)r * N + c];
        if (OUT_BF16)
          ((unsigned short*)C)[(size_t)r * N + c] = f2bf(val);
        else
          ((float*)C)[(size_t)r * N + c] = val;
      }
    }
  }
}

// ---- MFMA scores: 64x64 tile of (c2c + c2p + p2c)*scale, masked -------------
// c2p_full[iq,t] = Q[q0+iq] . pk[lo1+t]  (lo1 = q0-k0+512-63, t in [0,127])
// p2c_full[ik,t] = K[k0+ik] . pq[lo2+t]  (lo2 = k0-q0+512-63)
// scores[iq,ik] = c2c + c2p_full[iq, iq-ik+63] + p2c_full[ik, ik-iq+63]
__global__ __launch_bounds__(256)
void scores_mfma(const unsigned short* __restrict__ qb,
                 const unsigned short* __restrict__ kb,
                 const unsigned short* __restrict__ pk,
                 const unsigned short* __restrict__ pq,
                 const int* __restrict__ tok,
                 float* __restrict__ scores, int b0) {
  constexpr int RS = 72;    // phase-1 row stride (bf16 elems), 16B-aligned rows
  constexpr int TS = 130;   // phase-2 row stride
  __shared__ unsigned short sm[64 * RS * 2 + 128 * RS * 2];  // 55296 B
  unsigned short* Qs  = sm;                       // [64][RS]
  unsigned short* Ks  = sm + 64 * RS;             // [64][RS]
  unsigned short* PKb = sm + 128 * RS;            // [128][RS]
  unsigned short* PQb = sm + 128 * RS + 128 * RS; // [128][RS]
  unsigned short* c2pL = sm;                      // phase-2 alias [64][TS]
  unsigned short* p2cL = sm + 64 * TS;            // [64][TS]

  int t = threadIdx.x;
  int h = blockIdx.z % NH;
  int b = b0 + blockIdx.z / NH;
  int q0 = blockIdx.y * 64, k0 = blockIdx.x * 64;
  int wave = t >> 6, lane = t & 63;

  // ---- stage Q,K (64x64) and pk/pq bands (128x64) as bf16 ----
#pragma unroll
  for (int i = 0; i < 2; i++) {
    int c = t + i * 256;               // 0..511
    int r = c >> 3, d0 = (c & 7) * 8;
    *(s16x8*)&Qs[r * RS + d0] =
        *(const s16x8*)&qb[(size_t)(b * S + q0 + r) * HID + h * 64 + d0];
    *(s16x8*)&Ks[r * RS + d0] =
        *(const s16x8*)&kb[(size_t)(b * S + k0 + r) * HID + h * 64 + d0];
  }
  int lo1 = q0 - k0 + 512 - 63;
  int lo2 = k0 - q0 + 512 - 63;
#pragma unroll
  for (int i = 0; i < 4; i++) {
    int c = t + i * 256;               // 0..1023
    int tt = c >> 3, d0 = (c & 7) * 8;
    int r1 = lo1 + tt; r1 = r1 < 0 ? 0 : (r1 > M2 - 1 ? M2 - 1 : r1);
    int r2 = lo2 + tt; r2 = r2 < 0 ? 0 : (r2 > M2 - 1 ? M2 - 1 : r2);
    *(s16x8*)&PKb[tt * RS + d0] = *(const s16x8*)&pk[(size_t)r1 * HID + h * 64 + d0];
    *(s16x8*)&PQb[tt * RS + d0] = *(const s16x8*)&pq[(size_t)r2 * HID + h * 64 + d0];
  }
  __syncthreads();

  int wr = (wave >> 1) * 32, wc = (wave & 1) * 32;
  f32x4 c2c[2][2] = {};
  f32x4 cp[8] = {};
  f32x4 pc[8] = {};
  int rb = wave * 16 + (lane & 15);    // band-GEMM A-row (wave covers 16 rows)
#pragma unroll
  for (int ks = 0; ks < 2; ks++) {
    int koff = ks * 32 + (lane >> 4) * 8;
    s16x8 aq[2], bk2[2];
#pragma unroll
    for (int m = 0; m < 2; m++)
      aq[m] = *(const s16x8*)&Qs[(wr + m * 16 + (lane & 15)) * RS + koff];
#pragma unroll
    for (int n = 0; n < 2; n++)
      bk2[n] = *(const s16x8*)&Ks[(wc + n * 16 + (lane & 15)) * RS + koff];
#pragma unroll
    for (int m = 0; m < 2; m++)
#pragma unroll
      for (int n = 0; n < 2; n++)
        c2c[m][n] = __builtin_amdgcn_mfma_f32_16x16x32_bf16(aq[m], bk2[n],
                                                            c2c[m][n], 0, 0, 0);
    s16x8 aqb = *(const s16x8*)&Qs[rb * RS + koff];
    s16x8 akb = *(const s16x8*)&Ks[rb * RS + koff];
#pragma unroll
    for (int tt = 0; tt < 8; tt++) {
      s16x8 bpk = *(const s16x8*)&PKb[(tt * 16 + (lane & 15)) * RS + koff];
      s16x8 bpq = *(const s16x8*)&PQb[(tt * 16 + (lane & 15)) * RS + koff];
      cp[tt] = __builtin_amdgcn_mfma_f32_16x16x32_bf16(aqb, bpk, cp[tt], 0, 0, 0);
      pc[tt] = __builtin_amdgcn_mfma_f32_16x16x32_bf16(akb, bpq, pc[tt], 0, 0, 0);
    }
  }
  __syncthreads();   // all phase-1 LDS reads complete before alias overwrite

  {
    int row = wave * 16 + ((lane >> 4) << 2);
#pragma unroll
    for (int tt = 0; tt < 8; tt++)
#pragma unroll
      for (int j = 0; j < 4; j++) {
        c2pL[(row + j) * TS + tt * 16 + (lane & 15)] = f2bf(cp[tt][j]);
        p2cL[(row + j) * TS + tt * 16 + (lane & 15)] = f2bf(pc[tt][j]);
      }
  }
  __syncthreads();

  const float scale = 0.07216878364870323f;   // 1/sqrt(3*64)
  size_t obase = ((size_t)(b - b0) * NH + h) * S * S;
#pragma unroll
  for (int m = 0; m < 2; m++) {
    int iqb = wr + m * 16 + ((lane >> 4) << 2);
#pragma unroll
    for (int n = 0; n < 2; n++) {
      int ik = wc + n * 16 + (lane & 15);
      bool msk = (tok[b * S + k0 + ik] == 0);
#pragma unroll
      for (int j = 0; j < 4; j++) {
        int iq = iqb + j;
        float v = c2c[m][n][j]
                + bf2f(c2pL[iq * TS + (iq - ik + 63)])
                + bf2f(p2cL[ik * TS + (ik - iq + 63)]);
        v *= scale;
        if (msk) v = -1e9f;
        scores[obase + (size_t)(q0 + iq) * S + (k0 + ik)] = v;
      }
    }
  }
}

// ---- row softmax over 512 keys; writes bf16 probs in-place ------------------
// probs row i occupies the first 1024 bytes of score row i (stride stays 2048B)
__global__ __launch_bounds__(256)
void softmax_kernel(float* __restrict__ scores, int nrows) {
  int wave = threadIdx.x >> 6, lane = threadIdx.x & 63;
  int row = blockIdx.x * 4 + wave;
  if (row >= nrows) return;
  float* p = scores + (size_t)row * S;
  float v[8];
  float mx = -1e30f;
#pragma unroll
  for (int i = 0; i < 8; i++) { v[i] = p[lane + i * 64]; mx = fmaxf(mx, v[i]); }
  mx = wave_max(mx);
  float s = 0.f;
#pragma unroll
  for (int i = 0; i < 8; i++) { v[i] = __expf(v[i] - mx); s += v[i]; }
  s = wave_sum(s);
  float inv = 1.0f / s;
  unsigned short* o = (unsigned short*)p;
#pragma unroll
  for (int i = 0; i < 8; i++) o[lane + i * 64] = f2bf(v[i] * inv);
}

// ---- V transpose: vb16 [B*S, HID] -> vt [B*NH*64, S] ------------------------
__global__ __launch_bounds__(256)
void transpose_v(const unsigned short* __restrict__ vb,
                 unsigned short* __restrict__ vt) {
  __shared__ unsigned short tile[32][34];
  int bh = blockIdx.z;
  int b = bh / NH, h = bh % NH;
  int s0 = blockIdx.x * 32, d0 = blockIdx.y * 32;
  int tx = threadIdx.x & 31, ty = threadIdx.x >> 5;
#pragma unroll
  for (int i = 0; i < 4; i++)
    tile[ty + i * 8][tx] =
        vb[(size_t)(b * S + s0 + ty + i * 8) * HID + h * 64 + d0 + tx];
  __syncthreads();
#pragma unroll
  for (int i = 0; i < 4; i++)
    vt[((size_t)bh * 64 + d0 + ty + i * 8) * S + s0 + tx] = tile[tx][ty + i * 8];
}

// ---- ctx = probs @ V via MFMA: per (b,h), 64q x 64d tile --------------------
__global__ __launch_bounds__(256)
void ctx_mfma(const float* __restrict__ scores,      // bf16 probs in-place
              const unsigned short* __restrict__ vt, // [B*NH*64, S]
              unsigned short* __restrict__ ctx, int b0) {
  constexpr int PS_ = 40;
  __shared__ unsigned short Ps[64 * PS_];
  __shared__ unsigned short Vs[64 * PS_];
  int h = blockIdx.y % NH;
  int bl = blockIdx.y / NH;
  int b = b0 + bl;
  int q0 = blockIdx.x * 64;
  int t = threadIdx.x, wave = t >> 6, lane = t & 63;
  const unsigned short* pr =
      (const unsigned short*)(scores + ((size_t)bl * NH + h) * S * S);
  const unsigned short* vh = vt + (size_t)(b * NH + h) * 64 * S;
  int wr = (wave >> 1) * 32, wc = (wave & 1) * 32;
  f32x4 acc[2][2] = {};
  int r = t >> 2, e0 = (t & 3) * 8;
  for (int k0 = 0; k0 < S; k0 += 32) {
    __syncthreads();
    *(s16x8*)&Ps[r * PS_ + e0] =
        *(const s16x8*)&pr[(size_t)(q0 + r) * 1024 + k0 + e0];
    *(s16x8*)&Vs[r * PS_ + e0] = *(const s16x8*)&vh[(size_t)r * S + k0 + e0];
    __syncthreads();
    int koff = (lane >> 4) * 8;
    s16x8 a[2], bv[2];
#pragma unroll
    for (int m = 0; m < 2; m++)
      a[m] = *(const s16x8*)&Ps[(wr + m * 16 + (lane & 15)) * PS_ + koff];
#pragma unroll
    for (int n = 0; n < 2; n++)
      bv[n] = *(const s16x8*)&Vs[(wc + n * 16 + (lane & 15)) * PS_ + koff];
#pragma unroll
    for (int m = 0; m < 2; m++)
#pragma unroll
      for (int n = 0; n < 2; n++)
        acc[m][n] = __builtin_amdgcn_mfma_f32_16x16x32_bf16(a[m], bv[n],
                                                            acc[m][n], 0, 0, 0);
  }
#pragma unroll
  for (int m = 0; m < 2; m++) {
    int iqb = wr + m * 16 + ((lane >> 4) << 2);
#pragma unroll
    for (int n = 0; n < 2; n++) {
      int dd = wc + n * 16 + (lane & 15);
#pragma unroll
      for (int j = 0; j < 4; j++) {
        int iq = iqb + j;
        ctx[(size_t)(b * S + q0 + iq) * HID + h * 64 + dd] = f2bf(acc[m][n][j]);
      }
    }
  }
}

// ---------------------------------------------------------------------------
extern "C" void kernel_launch(void* const* d_in, const int* in_sizes, int n_in,
                              void* d_out, int out_size, void* d_ws,
                              size_t ws_size, hipStream_t stream) {
  (void)in_sizes; (void)n_in; (void)out_size;
  const int*   tok     = (const int*)d_in[0];
  const int*   seg     = (const int*)d_in[1];
  const float* tok_emb = (const float*)d_in[2];
  const float* seg_emb = (const float*)d_in[3];
  const float* Wq  = (const float*)d_in[4];
  const float* bq  = (const float*)d_in[5];
  const float* Wk  = (const float*)d_in[6];
  const float* bk  = (const float*)d_in[7];
  const float* Wv  = (const float*)d_in[8];
  const float* bv  = (const float*)d_in[9];
  const float* Wo  = (const float*)d_in[10];
  const float* bo  = (const float*)d_in[11];
  const float* Wpk = (const float*)d_in[12];
  const float* Wpq = (const float*)d_in[13];
  const float* rel = (const float*)d_in[14];
  const float* ln1g = (const float*)d_in[15];
  const float* ln1b = (const float*)d_in[16];
  const float* ln2g = (const float*)d_in[17];
  const float* ln2b = (const float*)d_in[18];
  const float* W1  = (const float*)d_in[19];
  const float* b1  = (const float*)d_in[20];
  const float* W2  = (const float*)d_in[21];
  const float* b2  = (const float*)d_in[22];
  const float* lnfg = (const float*)d_in[23];
  const float* lnfb = (const float*)d_in[24];
  float* out = (float*)d_out;

  // ---- workspace layout ----
  char* base = (char*)d_ws;
  size_t off = 0;
  auto alloc = [&](size_t bytes) -> void* {
    void* p = base + off;
    off += (bytes + 255) & ~(size_t)255;
    return p;
  };
  const size_t XSZ = (size_t)NTOK * HID;
  float* x = (float*)alloc(XSZ * 4);
  unsigned short* qb16 = (unsigned short*)alloc(XSZ * 2);
  unsigned short* kb16 = (unsigned short*)alloc(XSZ * 2);
  unsigned short* vt16 = (unsigned short*)alloc(XSZ * 2);
  unsigned short* pk16 = (unsigned short*)alloc((size_t)M2 * HID * 2);
  unsigned short* pq16 = (unsigned short*)alloc((size_t)M2 * HID * 2);
  unsigned short* act16 = (unsigned short*)alloc(XSZ * 2);
  unsigned short* ff16  = (unsigned short*)alloc((size_t)NTOK * FF * 2);
  unsigned short* vb16  = ff16;   // alias: V (pre-transpose) dead before FFN
  unsigned short* rel16 = (unsigned short*)alloc((size_t)M2 * HID * 2);
  unsigned short* wt6   = (unsigned short*)alloc((size_t)6 * HID * HID * 2);
  unsigned short* wt1   = (unsigned short*)alloc((size_t)HID * FF * 2);
  unsigned short* wt2   = (unsigned short*)alloc((size_t)HID * FF * 2);
  size_t fixed = off;
  int nb = 1;
  for (int cand = 8; cand >= 1; cand >>= 1) {
    if (fixed + (size_t)cand * NH * S * S * 4 <= ws_size) { nb = cand; break; }
  }
  float* scores = (float*)alloc((size_t)nb * NH * S * S * 4);

  const size_t WSQ = (size_t)HID * HID;

  embed_kernel<<<NTOK, 256, 0, stream>>>(tok, seg, tok_emb, seg_emb, x);

  for (int l = 0; l < L; l++) {
    const float* lWq = Wq + (size_t)l * WSQ;
    const float* lWk = Wk + (size_t)l * WSQ;
    const float* lWv = Wv + (size_t)l * WSQ;
    const float* lWo = Wo + (size_t)l * WSQ;
    const float* lWpk = Wpk + (size_t)l * WSQ;
    const float* lWpq = Wpq + (size_t)l * WSQ;
    const float* lW1 = W1 + (size_t)l * HID * FF;
    const float* lW2 = W2 + (size_t)l * FF * HID;
    const float* lrel = rel + (size_t)l * M2 * HID;

    // weight prep (slots: 0=q 1=k 2=v 3=o 4=pk 5=pq)
    transpose6_kernel<<<dim3(HID / 32, HID / 32, 6), 256, 0, stream>>>(
        lWq, lWk, lWv, lWo, lWpk, lWpq, wt6);
    transpose_kernel<<<dim3(FF / 32, HID / 32), 256, 0, stream>>>(lW1, wt1, HID, FF);
    transpose_kernel<<<dim3(HID / 32, FF / 32), 256, 0, stream>>>(lW2, wt2, FF, HID);
    conv_bf16_kernel<<<(M2 * HID + 255) / 256, 256, 0, stream>>>(lrel, rel16, M2 * HID);

    // ---- attention sublayer (pre-norm) ----
    ln_kernel<1><<<NTOK / 4, 256, 0, stream>>>(x, act16, ln1g + l * HID,
                                               ln1b + l * HID, NTOK);
    mfma_gemm<1, 0><<<dim3(HID / 128, NTOK / 128), 256, 0, stream>>>(
        act16, wt6 + 0 * WSQ, bq + l * HID, nullptr, qb16, NTOK, HID, HID);
    mfma_gemm<1, 0><<<dim3(HID / 128, NTOK / 128), 256, 0, stream>>>(
        act16, wt6 + 1 * WSQ, bk + l * HID, nullptr, kb16, NTOK, HID, HID);
    mfma_gemm<1, 0><<<dim3(HID / 128, NTOK / 128), 256, 0, stream>>>(
        act16, wt6 + 2 * WSQ, bv + l * HID, nullptr, vb16, NTOK, HID, HID);
    mfma_gemm<1, 0><<<dim3(HID / 128, M2 / 128), 256, 0, stream>>>(
        rel16, wt6 + 4 * WSQ, nullptr, nullptr, pk16, M2, HID, HID);
    mfma_gemm<1, 0><<<dim3(HID / 128, M2 / 128), 256, 0, stream>>>(
        rel16, wt6 + 5 * WSQ, nullptr, nullptr, pq16, M2, HID, HID);
    transpose_v<<<dim3(S / 32, D / 32, B * NH), 256, 0, stream>>>(vb16, vt16);

    for (int b0 = 0; b0 < B; b0 += nb) {
      scores_mfma<<<dim3(S / 64, S / 64, nb * NH), 256, 0, stream>>>(
          qb16, kb16, pk16, pq16, tok, scores, b0);
      softmax_kernel<<<(nb * NH * S) / 4, 256, 0, stream>>>(scores, nb * NH * S);
      ctx_mfma<<<dim3(S / 64, nb * NH), 256, 0, stream>>>(scores, vt16, act16, b0);
    }
    mfma_gemm<0, 0><<<dim3(HID / 128, NTOK / 128), 256, 0, stream>>>(
        act16, wt6 + 3 * WSQ, bo + l * HID, x, x, NTOK, HID, HID);

    // ---- feedforward sublayer (pre-norm) ----
    ln_kernel<1><<<NTOK / 4, 256, 0, stream>>>(x, act16, ln2g + l * HID,
                                               ln2b + l * HID, NTOK);
    mfma_gemm<1, 1><<<dim3(FF / 128, NTOK / 128), 256, 0, stream>>>(
        act16, wt1, b1 + l * FF, nullptr, ff16, NTOK, HID, FF);
    mfma_gemm<0, 0><<<dim3(HID / 128, NTOK / 128), 256, 0, stream>>>(
        ff16, wt2, b2 + l * HID, x, x, NTOK, FF, HID);
  }

  ln_kernel<0><<<NTOK / 4, 256, 0, stream>>>(x, out, lnfg, lnfb, NTOK);
}

// Round 4
// 3967.124 us; speedup vs baseline: 5.1969x; 1.2661x over previous
//
#include <hip/hip_runtime.h>
#include <hip/hip_bf16.h>
#include <cstddef>
#include <cstdint>

// ---------------------------------------------------------------------------
// DeBERTa forward, MI355X. Round 4: fused QKV / TN=64 / split-K GEMMs +
// single-pass flash attention with DeBERTa band terms.
// B=8 S=512 HID=768 L=12 NH=12 D=64 FF=3072 2M=1024
// ---------------------------------------------------------------------------

constexpr int B   = 8;
constexpr int S   = 512;
constexpr int HID = 768;
constexpr int L   = 12;
constexpr int NH  = 12;
constexpr int D   = 64;
constexpr int FF  = 3072;
constexpr int M2  = 1024;          // 2*M
constexpr int NTOK = B * S;        // 4096

using f32x4 = __attribute__((ext_vector_type(4))) float;
using s16x8 = __attribute__((ext_vector_type(8))) short;

__device__ inline float wave_sum(float v) {
#pragma unroll
  for (int o = 32; o > 0; o >>= 1) v += __shfl_xor(v, o, 64);
  return v;
}
__device__ inline unsigned short f2bf(float f) {
  __hip_bfloat16 h = __float2bfloat16(f);
  return *reinterpret_cast<unsigned short*>(&h);
}
__device__ inline float bf2f(unsigned short u) {
  union { unsigned int i; float f; } x;
  x.i = ((unsigned int)u) << 16;
  return x.f;
}
#define GLOAD16(gp, lp)                                                  \
  __builtin_amdgcn_global_load_lds(                                     \
      (const __attribute__((address_space(1))) void*)(gp),              \
      (__attribute__((address_space(3))) void*)(lp), 16, 0, 0)

// ---- embeddings -------------------------------------------------------------
__global__ void embed_kernel(const int* __restrict__ tok,
                             const int* __restrict__ seg,
                             const float* __restrict__ tok_emb,
                             const float* __restrict__ seg_emb,
                             float* __restrict__ x) {
  int row = blockIdx.x;
  int s = row & (S - 1);
  int t = tok[row];
  int sg = seg[row];
  for (int c = threadIdx.x; c < HID; c += blockDim.x) {
    int i = c >> 1;
    float ang = (float)s * powf(10000.0f, -2.0f * (float)i / (float)HID);
    float pe = (c & 1) ? cosf(ang) : sinf(ang);
    x[(size_t)row * HID + c] = tok_emb[(size_t)t * HID + c] + pe
                             + seg_emb[(size_t)sg * HID + c];
  }
}

// ---- layernorm (one wave per row) -------------------------------------------
template <int BF16OUT>
__global__ __launch_bounds__(256)
void ln_kernel(const float* __restrict__ in, void* __restrict__ outp,
               const float* __restrict__ g, const float* __restrict__ b,
               int nrows) {
  int wave = threadIdx.x >> 6, lane = threadIdx.x & 63;
  int row = blockIdx.x * 4 + wave;
  if (row >= nrows) return;
  const float* xr = in + (size_t)row * HID;
  float v[12];
  float s = 0.f;
#pragma unroll
  for (int i = 0; i < 12; i++) { v[i] = xr[lane + i * 64]; s += v[i]; }
  s = wave_sum(s);
  float mu = s * (1.0f / HID);
  float ss = 0.f;
#pragma unroll
  for (int i = 0; i < 12; i++) { float d = v[i] - mu; ss += d * d; }
  ss = wave_sum(ss);
  float inv = rsqrtf(ss * (1.0f / HID) + 1e-5f);
#pragma unroll
  for (int i = 0; i < 12; i++) {
    int c = lane + i * 64;
    float o = (v[i] - mu) * inv * g[c] + b[c];
    if (BF16OUT)
      ((unsigned short*)outp)[(size_t)row * HID + c] = f2bf(o);
    else
      ((float*)outp)[(size_t)row * HID + c] = o;
  }
}

// ---- transpose+convert: src [K,N] f32 -> dst [N,K] bf16 ---------------------
__global__ __launch_bounds__(256)
void transpose_kernel(const float* __restrict__ src,
                      unsigned short* __restrict__ dst, int K, int N) {
  __shared__ float tile[32][33];
  int nt = blockIdx.x * 32, kt = blockIdx.y * 32;
  int tx = threadIdx.x & 31, ty = threadIdx.x >> 5;
#pragma unroll
  for (int i = 0; i < 4; i++)
    tile[ty + i * 8][tx] = src[(size_t)(kt + ty + i * 8) * N + nt + tx];
  __syncthreads();
#pragma unroll
  for (int i = 0; i < 4; i++)
    dst[(size_t)(nt + ty + i * 8) * K + kt + tx] = f2bf(tile[tx][ty + i * 8]);
}

__global__ __launch_bounds__(256)
void transpose6_kernel(const float* s0, const float* s1, const float* s2,
                       const float* s3, const float* s4, const float* s5,
                       unsigned short* __restrict__ dst) {
  const float* srcs[6] = {s0, s1, s2, s3, s4, s5};
  const float* src = srcs[blockIdx.z];
  unsigned short* d = dst + (size_t)blockIdx.z * HID * HID;
  __shared__ float tile[32][33];
  int nt = blockIdx.x * 32, kt = blockIdx.y * 32;
  int tx = threadIdx.x & 31, ty = threadIdx.x >> 5;
#pragma unroll
  for (int i = 0; i < 4; i++)
    tile[ty + i * 8][tx] = src[(size_t)(kt + ty + i * 8) * HID + nt + tx];
  __syncthreads();
#pragma unroll
  for (int i = 0; i < 4; i++)
    d[(size_t)(nt + ty + i * 8) * HID + kt + tx] = f2bf(tile[tx][ty + i * 8]);
}

__global__ void conv_bf16_kernel(const float* __restrict__ src,
                                 unsigned short* __restrict__ dst, int n) {
  int i = blockIdx.x * 256 + threadIdx.x;
  if (i < n) dst[i] = f2bf(src[i]);
}

// ---- bias concat for fused QKV: bqkv[l][0:768]=bq, [768:1536]=bk, ... -------
__global__ void concat_bias(const float* __restrict__ bq,
                            const float* __restrict__ bk,
                            const float* __restrict__ bv,
                            float* __restrict__ bqkv) {
  int i = blockIdx.x * 256 + threadIdx.x;
  if (i >= L * 2304) return;
  int l = i / 2304, c = i % 2304;
  float v = (c < 768) ? bq[l * 768 + c]
          : (c < 1536) ? bk[l * 768 + c - 768] : bv[l * 768 + c - 1536];
  bqkv[i] = v;
}

// ---- bf16 MFMA GEMM, 128xTN tile, optional split-K partial ------------------
// A: [Mr,K] bf16 row-major.  Bt: [N,K] bf16 row-major.
template <int TN, int OUT_BF16, int GELU, int PARTIAL>
__global__ __launch_bounds__(256)
void mfma_gemm(const unsigned short* __restrict__ A,
               const unsigned short* __restrict__ Bt,
               const float* __restrict__ bias, const float* __restrict__ res,
               void* __restrict__ C, int Mr, int K, int N, int Kc) {
  constexpr int NW = TN / 32;              // B frags per wave (4 or 2)
  __shared__ unsigned short As[128 * 32];
  __shared__ unsigned short Bs[TN * 32];
  int t = threadIdx.x, wave = t >> 6, lane = t & 63;
  int r0 = blockIdx.y * 128, n0 = blockIdx.x * TN;
  int kb = blockIdx.z * Kc;
  int wr = (wave >> 1) * 64;
  int wc = (wave & 1) * (TN / 2);

  f32x4 acc[4][NW] = {};
  int srow = lane >> 2, selem = (lane & 3) * 8;

  for (int k0 = kb; k0 < kb + Kc; k0 += 32) {
    __syncthreads();
    {
      const unsigned short* gA =
          A + (size_t)(r0 + wave * 32 + srow) * K + k0 + selem;
      unsigned short* lA = &As[(wave * 32) * 32];
      GLOAD16(gA, lA);
      GLOAD16(gA + (size_t)16 * K, lA + 16 * 32);
      if (TN == 128) {
        const unsigned short* gB =
            Bt + (size_t)(n0 + wave * 32 + srow) * K + k0 + selem;
        unsigned short* lB = &Bs[(wave * 32) * 32];
        GLOAD16(gB, lB);
        GLOAD16(gB + (size_t)16 * K, lB + 16 * 32);
      } else {
        const unsigned short* gB =
            Bt + (size_t)(n0 + wave * 16 + srow) * K + k0 + selem;
        GLOAD16(gB, &Bs[(wave * 16) * 32]);
      }
    }
    __syncthreads();

    s16x8 af[4], bf[NW];
#pragma unroll
    for (int m = 0; m < 4; m++)
      af[m] = *(const s16x8*)&As[(wr + m * 16 + (lane & 15)) * 32 + (lane >> 4) * 8];
#pragma unroll
    for (int n = 0; n < NW; n++)
      bf[n] = *(const s16x8*)&Bs[(wc + n * 16 + (lane & 15)) * 32 + (lane >> 4) * 8];
#pragma unroll
    for (int m = 0; m < 4; m++)
#pragma unroll
      for (int n = 0; n < NW; n++)
        acc[m][n] = __builtin_amdgcn_mfma_f32_16x16x32_bf16(af[m], bf[n],
                                                            acc[m][n], 0, 0, 0);
  }

  if (PARTIAL) {
    float* Cp = (float*)C + (size_t)blockIdx.z * Mr * N;
#pragma unroll
    for (int n = 0; n < NW; n++) {
      int c = n0 + wc + n * 16 + (lane & 15);
#pragma unroll
      for (int m = 0; m < 4; m++) {
        int rb = r0 + wr + m * 16 + ((lane >> 4) << 2);
#pragma unroll
        for (int j = 0; j < 4; j++)
          Cp[(size_t)(rb + j) * N + c] = acc[m][n][j];
      }
    }
    return;
  }
#pragma unroll
  for (int n = 0; n < NW; n++) {
    int c = n0 + wc + n * 16 + (lane & 15);
    float bv = bias ? bias[c] : 0.f;
#pragma unroll
    for (int m = 0; m < 4; m++) {
      int rb = r0 + wr + m * 16 + ((lane >> 4) << 2);
#pragma unroll
      for (int j = 0; j < 4; j++) {
        int r = rb + j;
        float val = acc[m][n][j] + bv;
        if (GELU) val = 0.5f * val * (1.0f + erff(val * 0.70710678118654752f));
        if (res)  val += res[(size_t)r * N + c];
        if (OUT_BF16)
          ((unsigned short*)C)[(size_t)r * N + c] = f2bf(val);
        else
          ((float*)C)[(size_t)r * N + c] = val;
      }
    }
  }
}

// ---- split-K combine + residual + LN (next layer's ln1, or final lnf) -------
template <int LAST>
__global__ __launch_bounds__(256)
void combine_ln(const float* __restrict__ part,   // [2][NTOK][HID]
                float* __restrict__ x, const float* __restrict__ bias,
                const float* __restrict__ g, const float* __restrict__ bb,
                void* __restrict__ outp) {
  int row = blockIdx.x, t = threadIdx.x;
  int wave = t >> 6, lane = t & 63;
  __shared__ float red[4];
  float v[3];
  float s = 0.f;
#pragma unroll
  for (int i = 0; i < 3; i++) {
    int c = t + i * 256;
    size_t idx = (size_t)row * HID + c;
    float val = x[idx] + part[idx] + part[(size_t)NTOK * HID + idx] + bias[c];
    if (!LAST) x[idx] = val;
    v[i] = val;
    s += val;
  }
  s = wave_sum(s);
  if (lane == 0) red[wave] = s;
  __syncthreads();
  float mu = (red[0] + red[1] + red[2] + red[3]) * (1.0f / HID);
  float ss = 0.f;
#pragma unroll
  for (int i = 0; i < 3; i++) { float d = v[i] - mu; ss += d * d; }
  ss = wave_sum(ss);
  __syncthreads();
  if (lane == 0) red[wave] = ss;
  __syncthreads();
  float inv = rsqrtf((red[0] + red[1] + red[2] + red[3]) * (1.0f / HID) + 1e-5f);
#pragma unroll
  for (int i = 0; i < 3; i++) {
    int c = t + i * 256;
    float o = (v[i] - mu) * inv * g[c] + bb[c];
    if (LAST)
      ((float*)outp)[(size_t)row * HID + c] = o;
    else
      ((unsigned short*)outp)[(size_t)row * HID + c] = f2bf(o);
  }
}

// ---- V transpose from fused qkv: qkv[.,1536+h*64+d] -> vt [bh*64+d][S] ------
__global__ __launch_bounds__(256)
void transpose_v(const unsigned short* __restrict__ qkv,
                 unsigned short* __restrict__ vt) {
  __shared__ unsigned short tile[32][34];
  int bh = blockIdx.z;
  int b = bh / NH, h = bh % NH;
  int s0 = blockIdx.x * 32, d0 = blockIdx.y * 32;
  int tx = threadIdx.x & 31, ty = threadIdx.x >> 5;
#pragma unroll
  for (int i = 0; i < 4; i++)
    tile[ty + i * 8][tx] =
        qkv[(size_t)(b * S + s0 + ty + i * 8) * 2304 + 1536 + h * 64 + d0 + tx];
  __syncthreads();
#pragma unroll
  for (int i = 0; i < 4; i++)
    vt[((size_t)bh * 64 + d0 + ty + i * 8) * S + s0 + tx] = tile[tx][ty + i * 8];
}

// ---- flash attention with DeBERTa band terms --------------------------------
// block: 256 thr = 4 waves, one (b,h,q0) tile of 64 q-rows; loop 8 k-tiles.
// wave w owns q-rows [w*16, w*16+16) (and k-rows likewise for the p2c band).
__global__ __launch_bounds__(256)
void flash_attn(const unsigned short* __restrict__ qkv,
                const unsigned short* __restrict__ pkq,  // [1024][1536] pk|pq
                const unsigned short* __restrict__ vt,   // [B*NH*64][S]
                const int* __restrict__ tok,
                unsigned short* __restrict__ ctx) {
  constexpr int RS = 72, TS = 130;
  __shared__ unsigned short Qs[64 * RS];
  __shared__ unsigned short KPs[64 * RS];       // K tile; aliased to P
  __shared__ unsigned short Vs[64 * RS];        // V^T tile [d][k]
  __shared__ unsigned short Band[2 * 128 * RS]; // PKb|PQb; aliased c2pL|p2cL
  __shared__ int smTok[64];
  unsigned short* PKb = Band;
  unsigned short* PQb = Band + 128 * RS;
  unsigned short* c2pL = Band;                  // [64][TS]
  unsigned short* p2cL = Band + 64 * TS;

  int t = threadIdx.x, wave = t >> 6, lane = t & 63;
  int bh = blockIdx.y;
  int b = bh / NH, h = bh % NH;
  int q0 = blockIdx.x * 64;
  int l15 = lane & 15, l4 = lane >> 4;

#pragma unroll
  for (int i = 0; i < 2; i++) {
    int c = t + i * 256;
    int r = c >> 3, d0 = (c & 7) * 8;
    *(s16x8*)&Qs[r * RS + d0] =
        *(const s16x8*)&qkv[(size_t)(b * S + q0 + r) * 2304 + h * 64 + d0];
  }

  float m[4], l[4];
  f32x4 accO[4];
#pragma unroll
  for (int j = 0; j < 4; j++) { m[j] = -1e30f; l[j] = 0.f; }
#pragma unroll
  for (int n = 0; n < 4; n++) accO[n] = (f32x4){0.f, 0.f, 0.f, 0.f};

  const float scale = 0.07216878364870323f;   // 1/sqrt(3*64)

  for (int k0 = 0; k0 < S; k0 += 64) {
    // ---- stage K, V^T, bands, tok mask ----
#pragma unroll
    for (int i = 0; i < 2; i++) {
      int c = t + i * 256;
      int r = c >> 3, d0 = (c & 7) * 8;
      *(s16x8*)&KPs[r * RS + d0] =
          *(const s16x8*)&qkv[(size_t)(b * S + k0 + r) * 2304 + 768 + h * 64 + d0];
      *(s16x8*)&Vs[r * RS + d0] =
          *(const s16x8*)&vt[((size_t)bh * 64 + r) * S + k0 + d0];
    }
    int lo1 = q0 - k0 + 449;
    int lo2 = k0 - q0 + 449;
#pragma unroll
    for (int i = 0; i < 4; i++) {
      int c = t + i * 256;
      int tt = c >> 3, d0 = (c & 7) * 8;
      int r1 = lo1 + tt; r1 = r1 < 0 ? 0 : (r1 > M2 - 1 ? M2 - 1 : r1);
      int r2 = lo2 + tt; r2 = r2 < 0 ? 0 : (r2 > M2 - 1 ? M2 - 1 : r2);
      *(s16x8*)&PKb[tt * RS + d0] = *(const s16x8*)&pkq[(size_t)r1 * 1536 + h * 64 + d0];
      *(s16x8*)&PQb[tt * RS + d0] =
          *(const s16x8*)&pkq[(size_t)r2 * 1536 + 768 + h * 64 + d0];
    }
    if (t < 64) smTok[t] = tok[b * S + k0 + t];
    __syncthreads();                                  // (1) staging visible

    // ---- MFMAs: c2c (QK^T), cp (Q.pk band), pc (K.pq band) ----
    f32x4 c2c[4] = {};
    f32x4 cp[8] = {}, pc[8] = {};
#pragma unroll
    for (int ks = 0; ks < 2; ks++) {
      int koff = ks * 32 + l4 * 8;
      s16x8 aq = *(const s16x8*)&Qs[(wave * 16 + l15) * RS + koff];
      s16x8 ak = *(const s16x8*)&KPs[(wave * 16 + l15) * RS + koff];
#pragma unroll
      for (int n = 0; n < 4; n++) {
        s16x8 bk = *(const s16x8*)&KPs[(n * 16 + l15) * RS + koff];
        c2c[n] = __builtin_amdgcn_mfma_f32_16x16x32_bf16(aq, bk, c2c[n], 0, 0, 0);
      }
#pragma unroll
      for (int tt = 0; tt < 8; tt++) {
        s16x8 bpk = *(const s16x8*)&PKb[(tt * 16 + l15) * RS + koff];
        s16x8 bpq = *(const s16x8*)&PQb[(tt * 16 + l15) * RS + koff];
        cp[tt] = __builtin_amdgcn_mfma_f32_16x16x32_bf16(aq, bpk, cp[tt], 0, 0, 0);
        pc[tt] = __builtin_amdgcn_mfma_f32_16x16x32_bf16(ak, bpq, pc[tt], 0, 0, 0);
      }
    }
    __syncthreads();                                  // (2) band reads done

    {
      int rw = wave * 16 + (l4 << 2);
#pragma unroll
      for (int tt = 0; tt < 8; tt++)
#pragma unroll
        for (int j = 0; j < 4; j++) {
          c2pL[(rw + j) * TS + tt * 16 + l15] = f2bf(cp[tt][j]);
          p2cL[(rw + j) * TS + tt * 16 + l15] = f2bf(pc[tt][j]);
        }
    }
    __syncthreads();                                  // (3) bands visible

    // ---- gather + mask + online softmax (wave's 16 q-rows) ----
    float p[4][4];
    float rmax[4];
#pragma unroll
    for (int j = 0; j < 4; j++) rmax[j] = -1e30f;
#pragma unroll
    for (int n = 0; n < 4; n++) {
      int ik = n * 16 + l15;
      bool msk = (smTok[ik] == 0);
#pragma unroll
      for (int j = 0; j < 4; j++) {
        int iq = wave * 16 + (l4 << 2) + j;
        float sc = c2c[n][j]
                 + bf2f(c2pL[iq * TS + (iq - ik + 63)])
                 + bf2f(p2cL[ik * TS + (ik - iq + 63)]);
        sc *= scale;
        if (msk) sc = -1e9f;
        p[n][j] = sc;
        rmax[j] = fmaxf(rmax[j], sc);
      }
    }
#pragma unroll
    for (int o = 8; o > 0; o >>= 1)
#pragma unroll
      for (int j = 0; j < 4; j++)
        rmax[j] = fmaxf(rmax[j], __shfl_xor(rmax[j], o, 64));
    float al[4];
#pragma unroll
    for (int j = 0; j < 4; j++) {
      float mn = fmaxf(m[j], rmax[j]);
      al[j] = __expf(m[j] - mn);
      m[j] = mn;
    }
    float rs[4] = {0.f, 0.f, 0.f, 0.f};
#pragma unroll
    for (int n = 0; n < 4; n++)
#pragma unroll
      for (int j = 0; j < 4; j++) {
        p[n][j] = __expf(p[n][j] - m[j]);
        rs[j] += p[n][j];
      }
#pragma unroll
    for (int o = 8; o > 0; o >>= 1)
#pragma unroll
      for (int j = 0; j < 4; j++) rs[j] += __shfl_xor(rs[j], o, 64);
#pragma unroll
    for (int j = 0; j < 4; j++) l[j] = l[j] * al[j] + rs[j];
#pragma unroll
    for (int n = 0; n < 4; n++)
#pragma unroll
      for (int j = 0; j < 4; j++) accO[n][j] *= al[j];

    // ---- P -> LDS (alias over KPs) in [q][k] layout ----
    {
      int rw = wave * 16 + (l4 << 2);
#pragma unroll
      for (int n = 0; n < 4; n++)
#pragma unroll
        for (int j = 0; j < 4; j++)
          KPs[(rw + j) * RS + n * 16 + l15] = f2bf(p[n][j]);
    }
    __syncthreads();                                  // (4) P visible

    // ---- PV: accO += P @ V ----
#pragma unroll
    for (int ks = 0; ks < 2; ks++) {
      int koff = ks * 32 + l4 * 8;
      s16x8 ap = *(const s16x8*)&KPs[(wave * 16 + l15) * RS + koff];
#pragma unroll
      for (int n = 0; n < 4; n++) {
        s16x8 bv2 = *(const s16x8*)&Vs[(n * 16 + l15) * RS + koff];
        accO[n] = __builtin_amdgcn_mfma_f32_16x16x32_bf16(ap, bv2, accO[n], 0, 0, 0);
      }
    }
    __syncthreads();                                  // (5) P/V reads done
  }

  // ---- epilogue: O = accO / l ----
#pragma unroll
  for (int n = 0; n < 4; n++) {
    int dd = h * 64 + n * 16 + l15;
#pragma unroll
    for (int j = 0; j < 4; j++) {
      int iq = q0 + wave * 16 + (l4 << 2) + j;
      ctx[(size_t)(b * S + iq) * HID + dd] = f2bf(accO[n][j] / l[j]);
    }
  }
}

// ---------------------------------------------------------------------------
extern "C" void kernel_launch(void* const* d_in, const int* in_sizes, int n_in,
                              void* d_out, int out_size, void* d_ws,
                              size_t ws_size, hipStream_t stream) {
  (void)in_sizes; (void)n_in; (void)out_size; (void)ws_size;
  const int*   tok     = (const int*)d_in[0];
  const int*   seg     = (const int*)d_in[1];
  const float* tok_emb = (const float*)d_in[2];
  const float* seg_emb = (const float*)d_in[3];
  const float* Wq  = (const float*)d_in[4];
  const float* bq  = (const float*)d_in[5];
  const float* Wk  = (const float*)d_in[6];
  const float* bk  = (const float*)d_in[7];
  const float* Wv  = (const float*)d_in[8];
  const float* bv  = (const float*)d_in[9];
  const float* Wo  = (const float*)d_in[10];
  const float* bo  = (const float*)d_in[11];
  const float* Wpk = (const float*)d_in[12];
  const float* Wpq = (const float*)d_in[13];
  const float* rel = (const float*)d_in[14];
  const float* ln1g = (const float*)d_in[15];
  const float* ln1b = (const float*)d_in[16];
  const float* ln2g = (const float*)d_in[17];
  const float* ln2b = (const float*)d_in[18];
  const float* W1  = (const float*)d_in[19];
  const float* b1  = (const float*)d_in[20];
  const float* W2  = (const float*)d_in[21];
  const float* b2  = (const float*)d_in[22];
  const float* lnfg = (const float*)d_in[23];
  const float* lnfb = (const float*)d_in[24];
  float* out = (float*)d_out;

  // ---- workspace layout (~116 MB) ----
  char* base = (char*)d_ws;
  size_t off = 0;
  auto alloc = [&](size_t bytes) -> void* {
    void* p = base + off;
    off += (bytes + 255) & ~(size_t)255;
    return p;
  };
  const size_t XSZ = (size_t)NTOK * HID;
  float* x = (float*)alloc(XSZ * 4);
  unsigned short* qkv16 = (unsigned short*)alloc((size_t)NTOK * 2304 * 2);
  unsigned short* pkq16 = (unsigned short*)alloc((size_t)M2 * 1536 * 2);
  unsigned short* vt16  = (unsigned short*)alloc(XSZ * 2);
  unsigned short* act16 = (unsigned short*)alloc(XSZ * 2);
  unsigned short* ff16  = (unsigned short*)alloc((size_t)NTOK * FF * 2);
  unsigned short* rel16 = (unsigned short*)alloc((size_t)M2 * HID * 2);
  unsigned short* wt6   = (unsigned short*)alloc((size_t)6 * HID * HID * 2);
  unsigned short* wt1   = (unsigned short*)alloc((size_t)HID * FF * 2);
  unsigned short* wt2   = (unsigned short*)alloc((size_t)HID * FF * 2);
  float* skbuf = (float*)alloc((size_t)2 * NTOK * HID * 4);
  float* bqkv  = (float*)alloc((size_t)L * 2304 * 4);

  const size_t WSQ = (size_t)HID * HID;

  embed_kernel<<<NTOK, 256, 0, stream>>>(tok, seg, tok_emb, seg_emb, x);
  concat_bias<<<(L * 2304 + 255) / 256, 256, 0, stream>>>(bq, bk, bv, bqkv);
  ln_kernel<1><<<NTOK / 4, 256, 0, stream>>>(x, act16, ln1g, ln1b, NTOK);

  for (int l = 0; l < L; l++) {
    // ---- weight prep (slots: 0=q 1=k 2=v 3=o 4=pk 5=pq) ----
    transpose6_kernel<<<dim3(HID / 32, HID / 32, 6), 256, 0, stream>>>(
        Wq + l * WSQ, Wk + l * WSQ, Wv + l * WSQ, Wo + l * WSQ,
        Wpk + l * WSQ, Wpq + l * WSQ, wt6);
    transpose_kernel<<<dim3(FF / 32, HID / 32), 256, 0, stream>>>(
        W1 + (size_t)l * HID * FF, wt1, HID, FF);
    transpose_kernel<<<dim3(HID / 32, FF / 32), 256, 0, stream>>>(
        W2 + (size_t)l * FF * HID, wt2, FF, HID);
    conv_bf16_kernel<<<(M2 * HID + 255) / 256, 256, 0, stream>>>(
        rel + (size_t)l * M2 * HID, rel16, M2 * HID);

    // ---- attention ----
    mfma_gemm<128, 1, 0, 0><<<dim3(2304 / 128, NTOK / 128, 1), 256, 0, stream>>>(
        act16, wt6, bqkv + l * 2304, nullptr, qkv16, NTOK, HID, 2304, HID);
    mfma_gemm<64, 1, 0, 0><<<dim3(1536 / 64, M2 / 128, 1), 256, 0, stream>>>(
        rel16, wt6 + 4 * WSQ, nullptr, nullptr, pkq16, M2, HID, 1536, HID);
    transpose_v<<<dim3(S / 32, D / 32, B * NH), 256, 0, stream>>>(qkv16, vt16);
    flash_attn<<<dim3(S / 64, B * NH), 256, 0, stream>>>(
        qkv16, pkq16, vt16, tok, act16);
    mfma_gemm<64, 0, 0, 0><<<dim3(HID / 64, NTOK / 128, 1), 256, 0, stream>>>(
        act16, wt6 + 3 * WSQ, bo + l * HID, x, x, NTOK, HID, HID, HID);

    // ---- feedforward ----
    ln_kernel<1><<<NTOK / 4, 256, 0, stream>>>(x, act16, ln2g + l * HID,
                                               ln2b + l * HID, NTOK);
    mfma_gemm<128, 1, 1, 0><<<dim3(FF / 128, NTOK / 128, 1), 256, 0, stream>>>(
        act16, wt1, b1 + l * FF, nullptr, ff16, NTOK, HID, FF, HID);
    mfma_gemm<64, 0, 0, 1><<<dim3(HID / 64, NTOK / 128, 2), 256, 0, stream>>>(
        ff16, wt2, nullptr, nullptr, skbuf, NTOK, FF, HID, FF / 2);
    if (l < L - 1) {
      combine_ln<0><<<NTOK, 256, 0, stream>>>(
          skbuf, x, b2 + l * HID, ln1g + (l + 1) * HID, ln1b + (l + 1) * HID,
          act16);
    } else {
      combine_ln<1><<<NTOK, 256, 0, stream>>>(
          skbuf, x, b2 + l * HID, lnfg, lnfb, out);
    }
  }
}